// Round 5
// baseline (3967.375 us; speedup 1.0000x reference)
//
#include <hip/hip_runtime.h>
#include <stdint.h>

// MDLSTM2D: B=16, D0=D1=64, F=U=128, 5 gates (f0,f1,i,o,c)
// ROUND 13: R9-R12 falsified fence/staleness/contention; hop ~27.5us across
// four sync schemes. Invariant = critical-path SHAPE: each hop's consumer is
// a different cold block doing stage+proj+detect+h-load+k-loop serially after
// the producer. RESTRUCTURE using batch independence (batch b's recurrence
// never reads other batches): one block per (row i, batch-group g), wave w
// owns batch 4g+w, sweeps j=0..63. Left-dep (h_l,c_l) is wave-local (LDS/
// regs, ZERO sync). Up-dep: single-writer/single-reader progress counter per
// (row,batch); row i polls row i-1 >= j+1. Inter-block latency paid ~once per
// ROW (63 pipeline fills), not per cell (4095 hops). FMA order per (b,col)
// identical to R12 -> bit-identical output.

typedef float f32x2 __attribute__((ext_vector_type(2)));

#define SCOPE_AGENT __HIP_MEMORY_SCOPE_AGENT

__device__ __forceinline__ float sigm(float x) { return 1.f / (1.f + expf(-x)); }

__global__ void zero_prog(uint32_t* __restrict__ p) {
  p[blockIdx.x * 256 + threadIdx.x] = 0u;  // 64 blocks x 256 = 16384 words = 64KB
}

__global__ __launch_bounds__(256) void row_kernel(
    const float* __restrict__ x,
    const float* __restrict__ w0, const float* __restrict__ w1, const float* __restrict__ w2,
    const float* __restrict__ w3, const float* __restrict__ w4,
    const float* __restrict__ u0, const float* __restrict__ u1, const float* __restrict__ u2,
    const float* __restrict__ u3, const float* __restrict__ u4,
    const float* __restrict__ bb0, const float* __restrict__ bb1, const float* __restrict__ bb2,
    const float* __restrict__ bb3, const float* __restrict__ bb4,
    float* __restrict__ hbuf, float* __restrict__ cbuf,
    uint32_t* __restrict__ prog, float* __restrict__ out) {
  __shared__ float xs[4][128];
  __shared__ float hu[4][128];
  __shared__ float hl[4][128];
  const int tid = threadIdx.x;
  const int w = tid >> 6;    // wave 0..3
  const int lane = tid & 63;
  const int bx = blockIdx.x; // 0..255
  const int i = bx >> 2;     // row 0..63
  const int g = bx & 3;      // batch group
  const int b = g * 4 + w;   // batch 0..15
  const int n0 = lane * 2;   // this lane's 2 output columns

  // zero left/up state (hu stays zero for i==0; overwritten per-j otherwise)
  *(f32x2*)&hl[w][n0] = (f32x2){0.f, 0.f};
  *(f32x2*)&hu[w][n0] = (f32x2){0.f, 0.f};

  // hoisted pointers / biases (same values every j -> arithmetic unchanged)
  const float* Wp0 = w0 + n0;
  const float* Wp1 = w1 + n0;
  const float* Wp2 = w2 + n0;
  const float* Wp3 = w3 + n0;
  const float* Wp4 = w4 + n0;
  const float* Up0 = u0 + n0;
  const float* Up1 = u1 + n0;
  const float* Up2 = u2 + n0;
  const float* Up3 = u3 + n0;
  const float* Up4 = u4 + n0;
  const float b0a = bb0[n0], b0b = bb0[n0 + 1];
  const float b1a = bb1[n0], b1b = bb1[n0 + 1];
  const float b2a = bb2[n0], b2b = bb2[n0 + 1];
  const float b3a = bb3[n0], b3b = bb3[n0 + 1];
  const float b4a = bb4[n0], b4b = bb4[n0 + 1];

  // progress counters: one 64B line per (row, batch); 1 writer, 1 poller
  const uint32_t* progUp = prog + ((size_t)(i - 1) * 16 + b) * 16;  // used iff i>0
  uint32_t* progMe = prog + ((size_t)i * 16 + b) * 16;

  const size_t xrow = (((size_t)b * 64 + i) * 64) * 128;        // + j*128 + n0
  const size_t hrowUp = i > 0 ? (((size_t)(i - 1) * 16 + b) * 64) * 128 : 0;
  const size_t hrowMe = (((size_t)i * 16 + b) * 64) * 128;
  const size_t orow = (((size_t)b * 64 + i) * 64) * 128;

  float cla = 0.f, clb = 0.f;   // own-col c from previous column (c_l)
  uint32_t seen = 0;            // cached view of progUp (uniform across lanes)

  for (int j = 0; j < 64; ++j) {
    // ---- 1. stage x (this wave's batch) ----
    const f32x2 xg = *(const f32x2*)(x + xrow + (size_t)j * 128 + n0);
    *(f32x2*)&xs[w][n0] = xg;

    // ---- 2. projection for this lane's 2 cols, 5 gates (off critical path:
    // runs before the up-dep poll; left-dep not needed here) ----
    float p0a = b0a, p0b = b0b, p1a = b1a, p1b = b1b;
    float p2a = b2a, p2b = b2b, p3a = b3a, p3b = b3b;
    float p4a = b4a, p4b = b4b;
#pragma unroll 4
    for (int f = 0; f < 128; ++f) {
      const float xv = xs[w][f];
      const f32x2 t0 = *(const f32x2*)(Wp0 + f * 128);
      const f32x2 t1 = *(const f32x2*)(Wp1 + f * 128);
      const f32x2 t2 = *(const f32x2*)(Wp2 + f * 128);
      const f32x2 t3 = *(const f32x2*)(Wp3 + f * 128);
      const f32x2 t4 = *(const f32x2*)(Wp4 + f * 128);
      p0a += xv * t0[0]; p0b += xv * t0[1];
      p1a += xv * t1[0]; p1b += xv * t1[1];
      p2a += xv * t2[0]; p2b += xv * t2[1];
      p3a += xv * t3[0]; p3b += xv * t3[1];
      p4a += xv * t4[0]; p4b += xv * t4[1];
    }

    // ---- 3. up-dep: poll row i-1's progress (usually already satisfied) ----
    f32x2 cu = {0.f, 0.f};
    if (i > 0) {
      if (seen < (uint32_t)(j + 1)) {
        uint32_t v;
        do {
          v = __hip_atomic_load(progUp, __ATOMIC_RELAXED, SCOPE_AGENT);
          if (v < (uint32_t)(j + 1)) __builtin_amdgcn_s_sleep(1);
        } while (v < (uint32_t)(j + 1));
        seen = v;
      }
      // h_up -> LDS (512B per wave), c_up -> regs (own cols only)
      const unsigned long long hv = __hip_atomic_load(
          (const unsigned long long*)(hbuf + hrowUp + (size_t)j * 128 + n0),
          __ATOMIC_RELAXED, SCOPE_AGENT);
      *(f32x2*)&hu[w][n0] = __builtin_bit_cast(f32x2, hv);
      const unsigned long long cv = __hip_atomic_load(
          (const unsigned long long*)(cbuf + hrowUp + (size_t)j * 128 + n0),
          __ATOMIC_RELAXED, SCOPE_AGENT);
      cu = __builtin_bit_cast(f32x2, cv);
    }

    // ---- 4. recurrence: 5 matvecs over k (h_l from LDS = wave-local) ----
    float d0a = 0, d0b = 0, d1a = 0, d1b = 0, d2a = 0, d2b = 0;
    float d3a = 0, d3b = 0, d4a = 0, d4b = 0;
#pragma unroll 4
    for (int k = 0; k < 128; ++k) {
      const float a = hu[w][k], l = hl[w][k], s = a + l;
      const f32x2 t0 = *(const f32x2*)(Up0 + k * 128);
      const f32x2 t1 = *(const f32x2*)(Up1 + k * 128);
      const f32x2 t2 = *(const f32x2*)(Up2 + k * 128);
      const f32x2 t3 = *(const f32x2*)(Up3 + k * 128);
      const f32x2 t4 = *(const f32x2*)(Up4 + k * 128);
      d0a += a * t0[0]; d0b += a * t0[1];
      d1a += l * t1[0]; d1b += l * t1[1];
      d2a += s * t2[0]; d2b += s * t2[1];
      d3a += s * t3[0]; d3b += s * t3[1];
      d4a += s * t4[0]; d4b += s * t4[1];
    }

    // ---- 5. gates + state update (identical expressions/order) ----
    const float f0a = sigm(p0a + d0a), f0b = sigm(p0b + d0b);
    const float f1a = sigm(p1a + d1a), f1b = sigm(p1b + d1b);
    const float ita = sigm(p2a + d2a), itb = sigm(p2b + d2b);
    const float ota = sigm(p3a + d3a), otb = sigm(p3b + d3b);
    const float cpa = tanhf(p4a + d4a), cpb = tanhf(p4b + d4b);
    const float ca = f0a * cu[0] + f1a * cla + ita * cpa;
    const float cb = f0b * cu[1] + f1b * clb + itb * cpb;
    const float ha = ota * tanhf(ca), hb = otb * tanhf(cb);

    // ---- 6. stores ----
    *(f32x2*)(out + orow + (size_t)j * 128 + n0) = (f32x2){ha, hb};  // host-visible at kernel end
    if (i < 63) {
      __hip_atomic_store((unsigned long long*)(hbuf + hrowMe + (size_t)j * 128 + n0),
                         __builtin_bit_cast(unsigned long long, (f32x2){ha, hb}),
                         __ATOMIC_RELAXED, SCOPE_AGENT);
      __hip_atomic_store((unsigned long long*)(cbuf + hrowMe + (size_t)j * 128 + n0),
                         __builtin_bit_cast(unsigned long long, (f32x2){ca, cb}),
                         __ATOMIC_RELAXED, SCOPE_AGENT);
    }

    // ---- 7. roll left-state for next column (wave-local, no sync) ----
    *(f32x2*)&hl[w][n0] = (f32x2){ha, hb};
    cla = ca; clb = cb;

    // ---- 8. publish progress: drain this wave's sc1 stores, then bump ----
    if (i < 63) {
      asm volatile("s_waitcnt vmcnt(0)" ::: "memory");
      if (lane == 0)
        __hip_atomic_fetch_add(progMe, 1u, __ATOMIC_RELAXED, SCOPE_AGENT);
    }
  }
}

extern "C" void kernel_launch(void* const* d_in, const int* in_sizes, int n_in,
                              void* d_out, int out_size, void* d_ws, size_t ws_size,
                              hipStream_t stream) {
  const float* x = (const float*)d_in[0];
  const float* w0 = (const float*)d_in[1];
  const float* u0 = (const float*)d_in[2];
  const float* b0 = (const float*)d_in[3];
  const float* w1 = (const float*)d_in[4];
  const float* u1 = (const float*)d_in[5];
  const float* b1 = (const float*)d_in[6];
  const float* w2 = (const float*)d_in[7];
  const float* u2 = (const float*)d_in[8];
  const float* b2 = (const float*)d_in[9];
  const float* w3 = (const float*)d_in[10];
  const float* u3 = (const float*)d_in[11];
  const float* b3 = (const float*)d_in[12];
  const float* w4 = (const float*)d_in[13];
  const float* u4 = (const float*)d_in[14];
  const float* b4 = (const float*)d_in[15];

  char* ws = (char*)d_ws;
  // layout: prog 64KB (64 rows x 16 batches x 64B lines); hbuf 33.55MB; cbuf 33.55MB
  const size_t OFF_PROG = 0;
  const size_t OFF_H = 65536;
  const size_t OFF_C = OFF_H + (size_t)64 * 16 * 64 * 128 * 4;
  const size_t OFF_END = OFF_C + (size_t)64 * 16 * 64 * 128 * 4;
  if (ws_size < OFF_END) return;

  uint32_t* prog = (uint32_t*)(ws + OFF_PROG);
  float* hbuf = (float*)(ws + OFF_H);
  float* cbuf = (float*)(ws + OFF_C);
  float* out = (float*)d_out;

  hipLaunchKernelGGL(zero_prog, dim3(64), dim3(256), 0, stream, prog);

  void* args[] = {(void*)&x,  (void*)&w0, (void*)&w1, (void*)&w2, (void*)&w3, (void*)&w4,
                  (void*)&u0, (void*)&u1, (void*)&u2, (void*)&u3, (void*)&u4,
                  (void*)&b0, (void*)&b1, (void*)&b2, (void*)&b3, (void*)&b4,
                  (void*)&hbuf, (void*)&cbuf, (void*)&prog, (void*)&out};
  hipError_t e = hipLaunchCooperativeKernel((const void*)row_kernel, dim3(256),
                                            dim3(256), args, 0, stream);
  if (e != hipSuccess) {
    (void)hipGetLastError();  // 256 blocks always co-resident; plain launch is safe
    row_kernel<<<256, 256, 0, stream>>>(x, w0, w1, w2, w3, w4, u0, u1, u2, u3, u4,
                                        b0, b1, b2, b3, b4, hbuf, cbuf, prog, out);
  }
}